// Round 2
// baseline (297.964 us; speedup 1.0000x reference)
//
#include <hip/hip_runtime.h>
#include <stdint.h>

#define BATCH 16
#define NPROP 16384
#define NGT   128
#define NSAMP 256
#define NFG   64
#define GCAP  512
#define LCAP  8192

typedef unsigned long long ull;

// ---------- threefry2x32 block (key 0,1) ----------
__device__ __forceinline__ void thr_block(uint32_t c0, uint32_t c1,
                                          uint32_t* o0, uint32_t* o1) {
    const uint32_t k0 = 0u, k1 = 1u, ks2 = 0x1BD11BDBu; // 0^1^0x1BD11BDA
    uint32_t x0 = c0 + k0, x1 = c1 + k1;
#define RND(d) { x0 += x1; x1 = (x1 << d) | (x1 >> (32 - d)); x1 ^= x0; }
    RND(13) RND(15) RND(26) RND(6)   x0 += k1;  x1 += ks2 + 1u;
    RND(17) RND(29) RND(16) RND(24)  x0 += ks2; x1 += k0 + 2u;
    RND(13) RND(15) RND(26) RND(6)   x0 += k0;  x1 += k1 + 3u;
    RND(17) RND(29) RND(16) RND(24)  x0 += k1;  x1 += ks2 + 4u;
    RND(13) RND(15) RND(26) RND(6)   x0 += ks2; x1 += k0 + 5u;
#undef RND
    *o0 = x0; *o1 = x1;
}

__device__ __forceinline__ uint32_t thr_part_xor(uint32_t f) {
    uint32_t a, b; thr_block(0u, f, &a, &b);
    return a ^ b;
}

__global__ void k_zero(uint32_t* c) {
    if (threadIdx.x < 48) c[threadIdx.x] = 0u;
}

// list entry (u64): [44]=isPos, [43:21]=r mantissa (bits>>9), [20:7]=16383-n, [6:0]=argmax gt
// front region [0, npn): pos+neg.  back region (from 16383 downward): ignores.
__global__ void __launch_bounds__(256) k_compute(
    const float* __restrict__ props, const float* __restrict__ gts,
    ull* __restrict__ lists, uint32_t* __restrict__ cnts)
{
#pragma clang fp contract(off)
    const int b = blockIdx.y;
    const int tid = threadIdx.x;
    const int half = tid & 1;                 // 2 lanes per proposal: GTs 0-63 / 64-127
    const int n = blockIdx.x * 128 + (tid >> 1);
    __shared__ float4 g4[NGT];
    __shared__ float sag[NGT];
    if (tid < NGT) {
        float4 g = ((const float4*)gts)[(size_t)b * NGT + tid];
        g4[tid] = g;
        sag[tid] = (g.z - g.x) * (g.w - g.y);
    }
    __syncthreads();
    const float4 pb = ((const float4*)props)[(size_t)b * NPROP + n];
    const float ap = (pb.z - pb.x) * (pb.w - pb.y);
    float best = -1.0f; int bg = 0;
    const int gbase = half << 6;
    #pragma unroll 4
    for (int i = 0; i < 64; ++i) {
        const int gi = gbase + i;
        const float4 gb = g4[gi];
        float w  = fmaxf(fminf(pb.z, gb.z) - fmaxf(pb.x, gb.x), 0.0f);
        float hh = fmaxf(fminf(pb.w, gb.w) - fmaxf(pb.y, gb.y), 0.0f);
        float inter = w * hh;
        float un = fmaxf(ap + sag[gi] - inter, 1e-8f);
        float iou = inter / un;                 // IEEE f32 div = numpy bits
        if (iou > best) { best = iou; bg = gi; } // first-max within half
    }
    // merge halves: even lane owns result; strict > keeps half0 on fl-ties (lower gt idx)
    float ob = __shfl_xor(best, 1);
    int  obg = __shfl_xor(bg, 1);
    if ((tid & 1) == 0 && ob > best) { best = ob; bg = obg; }

    uint32_t lab = (best >= 0.5f) ? 2u : ((best < 0.1f) ? 1u : 0u);
    const uint32_t f = (uint32_t)b * NPROP + (uint32_t)n;
    uint32_t mant = thr_part_xor(f) >> 9;
    ull entry = ((ull)(lab == 2u) << 44) | ((ull)mant << 21)
              | ((ull)(16383u - (uint32_t)n) << 7) | (ull)(uint32_t)bg;

    const bool isEven = (tid & 1) == 0;
    bool front = isEven && (lab != 0u);
    bool back  = isEven && (lab == 0u);
    bool ispos = isEven && (lab == 2u);
    ull mF = __ballot(front), mB = __ballot(back), mP = __ballot(ispos);
    uint32_t lane = (uint32_t)tid & 63u;
    ull lt = lane ? (~0ull >> (64u - lane)) : 0ull;
    uint32_t bf = 0, bb = 0;
    if (lane == 0) {                      // wave-aggregated device atomics (<=3/wave)
        if (mF) bf = atomicAdd(&cnts[b],      (uint32_t)__popcll(mF));
        if (mB) bb = atomicAdd(&cnts[16 + b], (uint32_t)__popcll(mB));
        if (mP)      atomicAdd(&cnts[32 + b], (uint32_t)__popcll(mP));
    }
    bf = (uint32_t)__shfl((int)bf, 0);
    bb = (uint32_t)__shfl((int)bb, 0);
    ull* Lb = lists + (size_t)b * NPROP;
    if (front) Lb[bf + (uint32_t)__popcll(mF & lt)] = entry;
    if (back)  Lb[16383u - (bb + (uint32_t)__popcll(mB & lt))] = entry;
}

__global__ void __launch_bounds__(1024) k_select(
    const float* __restrict__ props, const float* __restrict__ gts,
    const ull* __restrict__ lists, const uint32_t* __restrict__ cnts,
    float* __restrict__ out)
{
#pragma clang fp contract(off)
    const int b = blockIdx.x;
    const int tid = threadIdx.x;
    __shared__ ull      sf[LCAP];        // 64 KB staged front list
    __shared__ uint32_t hist[2048];      // 8 KB
    __shared__ ull      gat[GCAP];       // 4 KB
    __shared__ ull      selk[NSAMP];     // 2 KB
    __shared__ uint32_t sela[NSAMP];     // 1 KB
    __shared__ uint32_t sh_dig, sh_k, sh_cnt_in, gcnt, selc;
    __shared__ ull sh_thr;

    const ull* Lb = lists + (size_t)b * NPROP;
    const uint32_t npn  = cnts[b];
    const uint32_t nig  = cnts[16 + b];
    const uint32_t npos = cnts[32 + b];
    const bool inLDS = (npn <= LCAP);
    if (inLDS) for (uint32_t j = tid; j < npn; j += 1024) sf[j] = Lb[j];
    if (tid == 0) selc = 0;
    __syncthreads();

    auto getF = [&](uint32_t j) -> ull { return inLDS ? sf[j] : Lb[j]; };
    auto keyA_of = [&](ull e) -> ull {   // raw (mant, invn): jnp stable argsort on r
        return (((e >> 21) & 0x7FFFFFull) << 14) | ((e >> 7) & 0x3FFFull);
    };

    auto locate = [&](uint32_t k) {      // boundary bin for k-th largest, wave 0
        if (tid < 64) {
            const uint32_t lane = (uint32_t)tid;
            uint32_t cs = 0;
            if (lane < 32) {
                const uint32_t base = lane * 64u;
                #pragma unroll 8
                for (uint32_t i = 0; i < 64; i++) cs += hist[base + i];
            }
            uint32_t s = cs;
            #pragma unroll
            for (int off = 1; off < 32; off <<= 1) {
                uint32_t t = __shfl_down(s, off);
                if (lane + off < 32) s += t;
            }
            uint32_t sExcl = s - cs;
            bool cond = (lane < 32) && (sExcl < k) && (k <= s);
            ull ball = __ballot(cond);
            uint32_t cstar = (uint32_t)(__ffsll((unsigned long long)ball) - 1);
            uint32_t kc = (uint32_t)__shfl((int)(k - sExcl), (int)cstar);
            uint32_t val = hist[cstar * 64u + lane];
            uint32_t fi = val;
            #pragma unroll
            for (int off = 1; off < 64; off <<= 1) {
                uint32_t t = __shfl_down(fi, off);
                if (lane + off < 64) fi += t;
            }
            uint32_t fExcl = fi - val;
            bool cond2 = (fExcl < kc) && (kc <= fi);
            ull ball2 = __ballot(cond2);
            uint32_t bstar = (uint32_t)(__ffsll((unsigned long long)ball2) - 1);
            if (lane == bstar) {
                sh_dig = cstar * 64u + lane;
                sh_k = kc - fExcl;
                sh_cnt_in = val;
            }
        }
    };

    // radix-select k-th largest over m list elements (key/elig via functor)
    auto radix = [&](auto&& kf, uint32_t m, uint32_t k, int shift) -> ull {
        ull prefix = 0, mask = 0;
        for (;;) {
            hist[tid] = 0; hist[tid + 1024] = 0;
            __syncthreads();
            for (uint32_t j = tid; j < m; j += 1024) {
                bool e; ull key = kf(j, e);
                if (e && ((key ^ prefix) & mask) == 0)
                    atomicAdd(&hist[(uint32_t)(key >> shift) & 2047u], 1u);
            }
            __syncthreads();
            locate(k);
            __syncthreads();
            uint32_t dig = sh_dig, kk = sh_k, cnt = sh_cnt_in;
            prefix |= ((ull)dig) << shift;
            mask   |= 2047ull << shift;
            if (cnt <= GCAP || shift == 0) {
                if (tid == 0) gcnt = 0;
                __syncthreads();
                for (uint32_t j = tid; j < m; j += 1024) {
                    bool e; ull key = kf(j, e);
                    if (e && ((key ^ prefix) & mask) == 0) {
                        uint32_t s = atomicAdd(&gcnt, 1u);
                        if (s < GCAP) gat[s] = key;
                    }
                }
                __syncthreads();
                uint32_t gc = (gcnt < GCAP) ? gcnt : GCAP;
                if (tid < (int)gc) {
                    ull x = gat[tid];
                    uint32_t r = 0;
                    for (uint32_t j = 0; j < gc; j++) r += (gat[j] > x);
                    if (r == kk - 1) sh_thr = x;
                }
                __syncthreads();
                return sh_thr;
            } else {
                k = kk;
                shift = (shift >= 11) ? shift - 11 : 0;
                __syncthreads();
            }
        }
    };

    // ---- phase 0: thrA = 64th-largest keyA among positives (only if npos > 64)
    ull thrA = 0;
    if (npos > NFG) {
        thrA = radix([&](uint32_t j, bool& e) -> ull {
            ull ent = getF(j);
            e = ((ent >> 44) & 1ull) != 0;
            return keyA_of(ent);
        }, npn, NFG, 26);
    }

    // exact jnp prio: f32 bits of (cls + r), rounding included (cls2 can hit 3.0f)
    auto keyB_of = [&](ull ent) -> ull {
        uint32_t mant = (uint32_t)((ent >> 21) & 0x7FFFFFull);
        uint32_t invn = (uint32_t)((ent >> 7) & 0x3FFFull);
        float r = __uint_as_float(0x3F800000u | mant) - 1.0f;
        uint32_t cls;
        if ((ent >> 44) & 1ull) cls = (keyA_of(ent) >= thrA) ? 3u : 1u;
        else cls = 2u;
        float prio = (float)cls + r;
        return (((ull)__float_as_uint(prio)) << 14) | (ull)invn;
    };
    auto key0_of = [&](ull ent) -> ull {   // ignores: cls 0, prio = r exactly
        uint32_t mant = (uint32_t)((ent >> 21) & 0x7FFFFFull);
        uint32_t invn = (uint32_t)((ent >> 7) & 0x3FFFull);
        float r = __uint_as_float(0x3F800000u | mant) - 1.0f;
        float prio = 0.0f + r;
        return (((ull)__float_as_uint(prio)) << 14) | (ull)invn;
    };

    // ---- phase 1: threshold for the 256-cut
    ull thrB = 0, thr0 = 0;
    uint32_t needIgn = 0;
    if (npn >= NSAMP) {
        thrB = radix([&](uint32_t j, bool& e) -> ull { e = true; return keyB_of(getF(j)); },
                     npn, NSAMP, 34);
    } else {                                // rare fallback: fill from ignores
        needIgn = NSAMP - npn;
        thr0 = radix([&](uint32_t j, bool& e) -> ull { e = true; return key0_of(Lb[16383u - j]); },
                     nig, needIgn, 34);
    }
    __syncthreads();

    // ---- compact: exactly NSAMP keys (keys unique)
    for (uint32_t j = tid; j < npn; j += 1024) {
        ull ent = getF(j);
        ull key = keyB_of(ent);
        if (npn < NSAMP || key >= thrB) {
            uint32_t s = atomicAdd(&selc, 1u);
            if (s < NSAMP) {
                selk[s] = key;
                sela[s] = ((uint32_t)((ent >> 44) & 1ull) << 7) | (uint32_t)(ent & 0x7Full);
            }
        }
    }
    if (needIgn) {
        for (uint32_t j = tid; j < nig; j += 1024) {
            ull ent = Lb[16383u - j];
            ull key = key0_of(ent);
            if (key >= thr0) {
                uint32_t s = atomicAdd(&selc, 1u);
                if (s < NSAMP) {
                    selk[s] = key;                 // cls0 keyB == key0
                    sela[s] = (uint32_t)(ent & 0x7Full);
                }
            }
        }
    }
    __syncthreads();

    // ---- rank-scatter: output row = count of greater keys (desc sort position)
    if (tid < NSAMP) {
        ull x = selk[tid];
        uint32_t r = 0;
        for (int j = 0; j < NSAMP; j++) r += (selk[j] > x);
        uint32_t n = 16383u - (uint32_t)(x & 0x3FFFull);
        uint32_t aux = sela[tid];
        uint32_t bg = aux & 0x7Fu;
        const int isfg = (int)((aux >> 7) & 1u);   // original label==1 (any positive)
        const float4 pb = ((const float4*)props)[(size_t)b * NPROP + n];
        const float4 gb = ((const float4*)gts)[(size_t)b * NGT + bg];
        const size_t O_ROI = 0;
        const size_t O_LBL = (size_t)BATCH * NSAMP * 4;
        const size_t O_TGT = O_LBL + (size_t)BATCH * NSAMP;
        const size_t O_INW = O_TGT + (size_t)BATCH * NSAMP * 4;
        const size_t O_OUW = O_INW + (size_t)BATCH * NSAMP * 4;
        const size_t row = (size_t)b * NSAMP + r;
        out[O_ROI + row * 4 + 0] = pb.x;
        out[O_ROI + row * 4 + 1] = pb.y;
        out[O_ROI + row * 4 + 2] = pb.z;
        out[O_ROI + row * 4 + 3] = pb.w;
        out[O_LBL + row] = isfg ? 1.0f : 0.0f;
        float rw  = pb.z - pb.x, rh = pb.w - pb.y;
        float gw  = gb.z - gb.x, gh = gb.w - gb.y;
        out[O_TGT + row * 4 + 0] = ((gb.x + gb.z) * 0.5f - (pb.x + pb.z) * 0.5f) / rw;
        out[O_TGT + row * 4 + 1] = ((gb.y + gb.w) * 0.5f - (pb.y + pb.w) * 0.5f) / rh;
        out[O_TGT + row * 4 + 2] = logf(gw / rw);
        out[O_TGT + row * 4 + 3] = logf(gh / rh);
        float wv = isfg ? 1.0f : 0.0f;
        for (int c = 0; c < 4; c++) {
            out[O_INW + row * 4 + c] = wv;
            out[O_OUW + row * 4 + c] = wv;
        }
    }
}

extern "C" void kernel_launch(void* const* d_in, const int* in_sizes, int n_in,
                              void* d_out, int out_size, void* d_ws, size_t ws_size,
                              hipStream_t stream) {
    (void)in_sizes; (void)n_in; (void)out_size; (void)ws_size;
    const float* props = (const float*)d_in[0];
    const float* gts   = (const float*)d_in[1];
    ull* lists = (ull*)d_ws;                                   // 16*16384*8B = 2 MB
    uint32_t* cnts = (uint32_t*)((char*)d_ws + (size_t)BATCH * NPROP * 8);  // 48 u32
    float* out = (float*)d_out;

    k_zero<<<1, 64, 0, stream>>>(cnts);
    dim3 gridA(NPROP / 128, BATCH);
    k_compute<<<gridA, 256, 0, stream>>>(props, gts, lists, cnts);
    k_select<<<BATCH, 1024, 0, stream>>>(props, gts, lists, cnts, out);
}

// Round 3
// 103.746 us; speedup vs baseline: 2.8721x; 2.8721x over previous
//
#include <hip/hip_runtime.h>
#include <stdint.h>

#define BATCH 16
#define NPROP 16384
#define NGT   128
#define NSAMP 256
#define NFG   64
#define GCAP  512
#define LCAP  8192
#define CSTR  32   // counter stride per batch (128B -> one cacheline per batch)

typedef unsigned long long ull;

// ---------- threefry2x32 block (key 0,1) ----------
__device__ __forceinline__ void thr_block(uint32_t c0, uint32_t c1,
                                          uint32_t* o0, uint32_t* o1) {
    const uint32_t k0 = 0u, k1 = 1u, ks2 = 0x1BD11BDBu; // 0^1^0x1BD11BDA
    uint32_t x0 = c0 + k0, x1 = c1 + k1;
#define RND(d) { x0 += x1; x1 = (x1 << d) | (x1 >> (32 - d)); x1 ^= x0; }
    RND(13) RND(15) RND(26) RND(6)   x0 += k1;  x1 += ks2 + 1u;
    RND(17) RND(29) RND(16) RND(24)  x0 += ks2; x1 += k0 + 2u;
    RND(13) RND(15) RND(26) RND(6)   x0 += k0;  x1 += k1 + 3u;
    RND(17) RND(29) RND(16) RND(24)  x0 += k1;  x1 += ks2 + 4u;
    RND(13) RND(15) RND(26) RND(6)   x0 += ks2; x1 += k0 + 5u;
#undef RND
    *o0 = x0; *o1 = x1;
}

__device__ __forceinline__ uint32_t thr_part_xor(uint32_t f) {
    uint32_t a, b; thr_block(0u, f, &a, &b);
    return a ^ b;
}

__global__ void k_zero(uint32_t* c) {
    if (threadIdx.x < BATCH * CSTR) c[threadIdx.x] = 0u;
}

// list entry (u64): [44]=isPos, [43:21]=r mantissa (bits>>9), [20:7]=16383-n, [6:0]=argmax gt
// front region [0, npn): pos+neg.  back region (from 16383 downward): ignores.
__global__ void __launch_bounds__(256) k_compute(
    const float* __restrict__ props, const float* __restrict__ gts,
    ull* __restrict__ lists, uint32_t* __restrict__ cnts)
{
#pragma clang fp contract(off)
    const int b = blockIdx.y;
    const int tid = threadIdx.x;
    const int half = tid & 1;                 // 2 lanes per proposal: GTs 0-63 / 64-127
    const int n = blockIdx.x * 128 + (tid >> 1);
    // SoA GT tile, odd half at +65 so even/odd lanes hit disjoint banks (no conflicts)
    __shared__ float2 sA[130];   // (x1,y1)
    __shared__ float2 sB[130];   // (x2,y2)
    __shared__ float  sag[130];
    __shared__ uint32_t wcF[4], wcB[4], wcP[4];
    __shared__ uint32_t sEF[4], sEB[4], sBaseF, sBaseB;
    if (tid < NGT) {
        float4 g = ((const float4*)gts)[(size_t)b * NGT + tid];
        int idx = (tid < 64) ? tid : tid + 1;
        sA[idx] = make_float2(g.x, g.y);
        sB[idx] = make_float2(g.z, g.w);
        sag[idx] = (g.z - g.x) * (g.w - g.y);
    }
    __syncthreads();
    const float4 pb = ((const float4*)props)[(size_t)b * NPROP + n];
    const float ap = (pb.z - pb.x) * (pb.w - pb.y);
    float best = -1.0f; int bg = 0;
    const int base  = half ? 65 : 0;
    const int gbias = half ? 64 : 0;
    #pragma unroll 4
    for (int i = 0; i < 64; ++i) {
        const float2 a = sA[base + i];
        const float2 c = sB[base + i];
        float w  = fmaxf(fminf(pb.z, c.x) - fmaxf(pb.x, a.x), 0.0f);
        float hh = fmaxf(fminf(pb.w, c.y) - fmaxf(pb.y, a.y), 0.0f);
        float inter = w * hh;
        float un = fmaxf(ap + sag[base + i] - inter, 1e-8f);
        float iou = inter / un;                   // IEEE f32 div = numpy bits
        if (iou > best) { best = iou; bg = gbias + i; }  // first-max within half
    }
    // merge halves: even lane owns result; strict > keeps half0 on float-ties (lower gt idx)
    float ob = __shfl_xor(best, 1);
    int  obg = __shfl_xor(bg, 1);
    if (half == 0 && ob > best) { best = ob; bg = obg; }

    uint32_t lab = (best >= 0.5f) ? 2u : ((best < 0.1f) ? 1u : 0u);
    const uint32_t f = (uint32_t)b * NPROP + (uint32_t)n;
    uint32_t mant = thr_part_xor(f) >> 9;
    ull entry = ((ull)(lab == 2u) << 44) | ((ull)mant << 21)
              | ((ull)(16383u - (uint32_t)n) << 7) | (ull)(uint32_t)bg;

    const bool isEven = (half == 0);
    bool front = isEven && (lab != 0u);
    bool back  = isEven && (lab == 0u);
    bool ispos = isEven && (lab == 2u);
    ull mF = __ballot(front), mB = __ballot(back), mP = __ballot(ispos);
    const int w = tid >> 6;
    const uint32_t lane = (uint32_t)tid & 63u;
    if (lane == 0) {
        wcF[w] = (uint32_t)__popcll(mF);
        wcB[w] = (uint32_t)__popcll(mB);
        wcP[w] = (uint32_t)__popcll(mP);
    }
    __syncthreads();
    if (tid == 0) {        // block-aggregated: 2 returning atomics/block, padded lines
        uint32_t eF = 0, eB = 0, tP = 0;
        #pragma unroll
        for (int i = 0; i < 4; i++) {
            sEF[i] = eF; eF += wcF[i];
            sEB[i] = eB; eB += wcB[i];
            tP += wcP[i];
        }
        sBaseF = eF ? atomicAdd(&cnts[b * CSTR + 0], eF) : 0u;
        sBaseB = eB ? atomicAdd(&cnts[b * CSTR + 1], eB) : 0u;
        if (tP) atomicAdd(&cnts[b * CSTR + 2], tP);
    }
    __syncthreads();
    ull lt = lane ? (~0ull >> (64u - lane)) : 0ull;
    ull* Lb = lists + (size_t)b * NPROP;
    if (front) Lb[sBaseF + sEF[w] + (uint32_t)__popcll(mF & lt)] = entry;
    if (back)  Lb[16383u - (sBaseB + sEB[w] + (uint32_t)__popcll(mB & lt))] = entry;
}

__global__ void __launch_bounds__(1024) k_select(
    const float* __restrict__ props, const float* __restrict__ gts,
    const ull* __restrict__ lists, const uint32_t* __restrict__ cnts,
    float* __restrict__ out)
{
#pragma clang fp contract(off)
    const int b = blockIdx.x;
    const int tid = threadIdx.x;
    __shared__ ull      sf[LCAP];        // 64 KB staged front list
    __shared__ uint32_t hist[2048];      // 8 KB
    __shared__ ull      gat[GCAP];       // 4 KB
    __shared__ ull      selk[NSAMP];     // 2 KB
    __shared__ uint32_t sela[NSAMP];     // 1 KB
    __shared__ uint32_t sh_dig, sh_k, sh_cnt_in, gcnt, selc;
    __shared__ ull sh_thr;

    const ull* Lb = lists + (size_t)b * NPROP;
    const uint32_t npn  = cnts[b * CSTR + 0];
    const uint32_t nig  = cnts[b * CSTR + 1];
    const uint32_t npos = cnts[b * CSTR + 2];
    const bool inLDS = (npn <= LCAP);
    if (inLDS) for (uint32_t j = tid; j < npn; j += 1024) sf[j] = Lb[j];
    if (tid == 0) selc = 0;
    __syncthreads();

    auto getF = [&](uint32_t j) -> ull { return inLDS ? sf[j] : Lb[j]; };
    auto keyA_of = [&](ull e) -> ull {   // raw (mant, invn): jnp stable argsort on r
        return (((e >> 21) & 0x7FFFFFull) << 14) | ((e >> 7) & 0x3FFFull);
    };

    auto locate = [&](uint32_t k) {      // boundary bin for k-th largest, wave 0
        if (tid < 64) {
            const uint32_t lane = (uint32_t)tid;
            uint32_t cs = 0;
            if (lane < 32) {
                const uint32_t base = lane * 64u;
                #pragma unroll 8
                for (uint32_t i = 0; i < 64; i++) cs += hist[base + i];
            }
            uint32_t s = cs;
            #pragma unroll
            for (int off = 1; off < 32; off <<= 1) {
                uint32_t t = __shfl_down(s, off);
                if (lane + off < 32) s += t;
            }
            uint32_t sExcl = s - cs;
            bool cond = (lane < 32) && (sExcl < k) && (k <= s);
            ull ball = __ballot(cond);
            uint32_t cstar = (uint32_t)(__ffsll((unsigned long long)ball) - 1);
            uint32_t kc = (uint32_t)__shfl((int)(k - sExcl), (int)cstar);
            uint32_t val = hist[cstar * 64u + lane];
            uint32_t fi = val;
            #pragma unroll
            for (int off = 1; off < 64; off <<= 1) {
                uint32_t t = __shfl_down(fi, off);
                if (lane + off < 64) fi += t;
            }
            uint32_t fExcl = fi - val;
            bool cond2 = (fExcl < kc) && (kc <= fi);
            ull ball2 = __ballot(cond2);
            uint32_t bstar = (uint32_t)(__ffsll((unsigned long long)ball2) - 1);
            if (lane == bstar) {
                sh_dig = cstar * 64u + lane;
                sh_k = kc - fExcl;
                sh_cnt_in = val;
            }
        }
    };

    // radix-select k-th largest over m list elements (key/elig via functor)
    auto radix = [&](auto&& kf, uint32_t m, uint32_t k, int shift) -> ull {
        ull prefix = 0, mask = 0;
        for (;;) {
            hist[tid] = 0; hist[tid + 1024] = 0;
            __syncthreads();
            for (uint32_t j = tid; j < m; j += 1024) {
                bool e; ull key = kf(j, e);
                if (e && ((key ^ prefix) & mask) == 0)
                    atomicAdd(&hist[(uint32_t)(key >> shift) & 2047u], 1u);
            }
            __syncthreads();
            locate(k);
            __syncthreads();
            uint32_t dig = sh_dig, kk = sh_k, cnt = sh_cnt_in;
            prefix |= ((ull)dig) << shift;
            mask   |= 2047ull << shift;
            if (cnt <= GCAP || shift == 0) {
                if (tid == 0) gcnt = 0;
                __syncthreads();
                for (uint32_t j = tid; j < m; j += 1024) {
                    bool e; ull key = kf(j, e);
                    if (e && ((key ^ prefix) & mask) == 0) {
                        uint32_t s = atomicAdd(&gcnt, 1u);
                        if (s < GCAP) gat[s] = key;
                    }
                }
                __syncthreads();
                uint32_t gc = (gcnt < GCAP) ? gcnt : GCAP;
                if (tid < (int)gc) {
                    ull x = gat[tid];
                    uint32_t r = 0;
                    for (uint32_t j = 0; j < gc; j++) r += (gat[j] > x);
                    if (r == kk - 1) sh_thr = x;
                }
                __syncthreads();
                return sh_thr;
            } else {
                k = kk;
                shift = (shift >= 11) ? shift - 11 : 0;
                __syncthreads();
            }
        }
    };

    // ---- phase 0: thrA = 64th-largest keyA among positives (only if npos > 64)
    ull thrA = 0;
    if (npos > NFG) {
        thrA = radix([&](uint32_t j, bool& e) -> ull {
            ull ent = getF(j);
            e = ((ent >> 44) & 1ull) != 0;
            return keyA_of(ent);
        }, npn, NFG, 26);
    }

    // exact jnp prio: f32 bits of (cls + r), rounding included (cls2 can hit 3.0f)
    auto keyB_of = [&](ull ent) -> ull {
        uint32_t mant = (uint32_t)((ent >> 21) & 0x7FFFFFull);
        uint32_t invn = (uint32_t)((ent >> 7) & 0x3FFFull);
        float r = __uint_as_float(0x3F800000u | mant) - 1.0f;
        uint32_t cls;
        if ((ent >> 44) & 1ull) cls = (keyA_of(ent) >= thrA) ? 3u : 1u;
        else cls = 2u;
        float prio = (float)cls + r;
        return (((ull)__float_as_uint(prio)) << 14) | (ull)invn;
    };
    auto key0_of = [&](ull ent) -> ull {   // ignores: cls 0, prio = r exactly
        uint32_t mant = (uint32_t)((ent >> 21) & 0x7FFFFFull);
        uint32_t invn = (uint32_t)((ent >> 7) & 0x3FFFull);
        float r = __uint_as_float(0x3F800000u | mant) - 1.0f;
        float prio = 0.0f + r;
        return (((ull)__float_as_uint(prio)) << 14) | (ull)invn;
    };

    // ---- phase 1: threshold for the 256-cut
    ull thrB = 0, thr0 = 0;
    uint32_t needIgn = 0;
    if (npn >= NSAMP) {
        thrB = radix([&](uint32_t j, bool& e) -> ull { e = true; return keyB_of(getF(j)); },
                     npn, NSAMP, 34);
    } else {                                // rare fallback: fill from ignores
        needIgn = NSAMP - npn;
        thr0 = radix([&](uint32_t j, bool& e) -> ull { e = true; return key0_of(Lb[16383u - j]); },
                     nig, needIgn, 34);
    }
    __syncthreads();

    // ---- compact: exactly NSAMP keys (keys unique)
    for (uint32_t j = tid; j < npn; j += 1024) {
        ull ent = getF(j);
        ull key = keyB_of(ent);
        if (npn < NSAMP || key >= thrB) {
            uint32_t s = atomicAdd(&selc, 1u);
            if (s < NSAMP) {
                selk[s] = key;
                sela[s] = ((uint32_t)((ent >> 44) & 1ull) << 7) | (uint32_t)(ent & 0x7Full);
            }
        }
    }
    if (needIgn) {
        for (uint32_t j = tid; j < nig; j += 1024) {
            ull ent = Lb[16383u - j];
            ull key = key0_of(ent);
            if (key >= thr0) {
                uint32_t s = atomicAdd(&selc, 1u);
                if (s < NSAMP) {
                    selk[s] = key;                 // cls0 keyB == key0
                    sela[s] = (uint32_t)(ent & 0x7Full);
                }
            }
        }
    }
    __syncthreads();

    // ---- rank-scatter: output row = count of greater keys (desc sort position)
    if (tid < NSAMP) {
        ull x = selk[tid];
        uint32_t r = 0;
        for (int j = 0; j < NSAMP; j++) r += (selk[j] > x);
        uint32_t n = 16383u - (uint32_t)(x & 0x3FFFull);
        uint32_t aux = sela[tid];
        uint32_t bg = aux & 0x7Fu;
        const int isfg = (int)((aux >> 7) & 1u);   // original label==1 (any positive)
        const float4 pb = ((const float4*)props)[(size_t)b * NPROP + n];
        const float4 gb = ((const float4*)gts)[(size_t)b * NGT + bg];
        const size_t O_ROI = 0;
        const size_t O_LBL = (size_t)BATCH * NSAMP * 4;
        const size_t O_TGT = O_LBL + (size_t)BATCH * NSAMP;
        const size_t O_INW = O_TGT + (size_t)BATCH * NSAMP * 4;
        const size_t O_OUW = O_INW + (size_t)BATCH * NSAMP * 4;
        const size_t row = (size_t)b * NSAMP + r;
        out[O_ROI + row * 4 + 0] = pb.x;
        out[O_ROI + row * 4 + 1] = pb.y;
        out[O_ROI + row * 4 + 2] = pb.z;
        out[O_ROI + row * 4 + 3] = pb.w;
        out[O_LBL + row] = isfg ? 1.0f : 0.0f;
        float rw  = pb.z - pb.x, rh = pb.w - pb.y;
        float gw  = gb.z - gb.x, gh = gb.w - gb.y;
        out[O_TGT + row * 4 + 0] = ((gb.x + gb.z) * 0.5f - (pb.x + pb.z) * 0.5f) / rw;
        out[O_TGT + row * 4 + 1] = ((gb.y + gb.w) * 0.5f - (pb.y + pb.w) * 0.5f) / rh;
        out[O_TGT + row * 4 + 2] = logf(gw / rw);
        out[O_TGT + row * 4 + 3] = logf(gh / rh);
        float wv = isfg ? 1.0f : 0.0f;
        for (int c = 0; c < 4; c++) {
            out[O_INW + row * 4 + c] = wv;
            out[O_OUW + row * 4 + c] = wv;
        }
    }
}

extern "C" void kernel_launch(void* const* d_in, const int* in_sizes, int n_in,
                              void* d_out, int out_size, void* d_ws, size_t ws_size,
                              hipStream_t stream) {
    (void)in_sizes; (void)n_in; (void)out_size; (void)ws_size;
    const float* props = (const float*)d_in[0];
    const float* gts   = (const float*)d_in[1];
    ull* lists = (ull*)d_ws;                                   // 16*16384*8B = 2 MB
    uint32_t* cnts = (uint32_t*)((char*)d_ws + (size_t)BATCH * NPROP * 8);  // padded
    float* out = (float*)d_out;

    k_zero<<<1, BATCH * CSTR, 0, stream>>>(cnts);
    dim3 gridA(NPROP / 128, BATCH);
    k_compute<<<gridA, 256, 0, stream>>>(props, gts, lists, cnts);
    k_select<<<BATCH, 1024, 0, stream>>>(props, gts, lists, cnts, out);
}

// Round 4
// 96.233 us; speedup vs baseline: 3.0963x; 1.0781x over previous
//
#include <hip/hip_runtime.h>
#include <stdint.h>

#define BATCH 16
#define NPROP 16384
#define NGT   128
#define NSAMP 256
#define NFG   64
#define GCAP  512
#define CSTR  128          // per-batch counter stride (u32) -> each counter own line
#define NEGT  0x780002u    // neg high/low mant split; strict f32(2+r) separation (RNE)

typedef unsigned long long ull;

// ---------- threefry2x32 block (key 0,1) ----------
__device__ __forceinline__ void thr_block(uint32_t c0, uint32_t c1,
                                          uint32_t* o0, uint32_t* o1) {
    const uint32_t k0 = 0u, k1 = 1u, ks2 = 0x1BD11BDBu; // 0^1^0x1BD11BDA
    uint32_t x0 = c0 + k0, x1 = c1 + k1;
#define RND(d) { x0 += x1; x1 = (x1 << d) | (x1 >> (32 - d)); x1 ^= x0; }
    RND(13) RND(15) RND(26) RND(6)   x0 += k1;  x1 += ks2 + 1u;
    RND(17) RND(29) RND(16) RND(24)  x0 += ks2; x1 += k0 + 2u;
    RND(13) RND(15) RND(26) RND(6)   x0 += k0;  x1 += k1 + 3u;
    RND(17) RND(29) RND(16) RND(24)  x0 += k1;  x1 += ks2 + 4u;
    RND(13) RND(15) RND(26) RND(6)   x0 += ks2; x1 += k0 + 5u;
#undef RND
    *o0 = x0; *o1 = x1;
}

__device__ __forceinline__ uint32_t thr_part_xor(uint32_t f) {
    uint32_t a, b; thr_block(0u, f, &a, &b);
    return a ^ b;
}

__global__ void k_zero(uint32_t* c) {
    for (int i = threadIdx.x; i < BATCH * CSTR; i += 1024) c[i] = 0u;
}

// list entry (u64): [44]=isPos, [43:21]=r mantissa (bits>>9), [20:7]=16383-n, [6:0]=argmax gt
// slabs per batch: 0=pos, 1=negHigh (mant>=NEGT), 2=negLow, 3=ignore
__global__ void __launch_bounds__(256) k_compute(
    const float* __restrict__ props, const float* __restrict__ gts,
    ull* __restrict__ lists, uint32_t* __restrict__ cnts)
{
#pragma clang fp contract(off)
    const int b = blockIdx.y;
    const int tid = threadIdx.x;
    const int half = tid & 1;                 // 2 lanes per proposal: GTs 0-63 / 64-127
    const int n = blockIdx.x * 128 + (tid >> 1);
    // SoA GT tile, odd half at +65 so even/odd lanes hit disjoint banks (no conflicts)
    __shared__ float2 sA[130];   // (x1,y1)
    __shared__ float2 sB[130];   // (x2,y2)
    __shared__ float  sag[130];
    __shared__ uint32_t wc[4][4];   // [class][wave]
    __shared__ uint32_t we[4][4];   // exclusive within block
    __shared__ uint32_t sBase[4];
    if (tid < NGT) {
        float4 g = ((const float4*)gts)[(size_t)b * NGT + tid];
        int idx = (tid < 64) ? tid : tid + 1;
        sA[idx] = make_float2(g.x, g.y);
        sB[idx] = make_float2(g.z, g.w);
        sag[idx] = (g.z - g.x) * (g.w - g.y);
    }
    __syncthreads();
    const float4 pb = ((const float4*)props)[(size_t)b * NPROP + n];
    const float ap = (pb.z - pb.x) * (pb.w - pb.y);
    float best = -1.0f; int bg = 0;
    const int base  = half ? 65 : 0;
    const int gbias = half ? 64 : 0;
    #pragma unroll 4
    for (int i = 0; i < 64; ++i) {
        const float2 a = sA[base + i];
        const float2 c = sB[base + i];
        float w  = fmaxf(fminf(pb.z, c.x) - fmaxf(pb.x, a.x), 0.0f);
        float hh = fmaxf(fminf(pb.w, c.y) - fmaxf(pb.y, a.y), 0.0f);
        float inter = w * hh;
        float un = fmaxf(ap + sag[base + i] - inter, 1e-8f);
        float iou = inter / un;                   // IEEE f32 div = numpy bits
        if (iou > best) { best = iou; bg = gbias + i; }  // first-max within half
    }
    // merge halves: even lane owns result; strict > keeps half0 on float-ties (lower gt idx)
    float ob = __shfl_xor(best, 1);
    int  obg = __shfl_xor(bg, 1);
    if (half == 0 && ob > best) { best = ob; bg = obg; }

    uint32_t lab = (best >= 0.5f) ? 2u : ((best < 0.1f) ? 1u : 0u);
    const uint32_t f = (uint32_t)b * NPROP + (uint32_t)n;
    uint32_t mant = thr_part_xor(f) >> 9;
    ull entry = ((ull)(lab == 2u) << 44) | ((ull)mant << 21)
              | ((ull)(16383u - (uint32_t)n) << 7) | (ull)(uint32_t)bg;

    const bool isEven = (half == 0);
    bool cP = isEven && (lab == 2u);
    bool cH = isEven && (lab == 1u) && (mant >= NEGT);
    bool cL = isEven && (lab == 1u) && (mant <  NEGT);
    bool cI = isEven && (lab == 0u);
    ull mP = __ballot(cP), mH = __ballot(cH), mL = __ballot(cL), mI = __ballot(cI);
    const int w = tid >> 6;
    const uint32_t lane = (uint32_t)tid & 63u;
    if (lane == 0) {
        wc[0][w] = (uint32_t)__popcll(mP);
        wc[1][w] = (uint32_t)__popcll(mH);
        wc[2][w] = (uint32_t)__popcll(mL);
        wc[3][w] = (uint32_t)__popcll(mI);
    }
    __syncthreads();
    if (tid < 4) {   // 4 parallel returning atomics, each to its own cacheline
        uint32_t e = 0;
        #pragma unroll
        for (int i = 0; i < 4; i++) { we[tid][i] = e; e += wc[tid][i]; }
        sBase[tid] = e ? atomicAdd(&cnts[b * CSTR + tid * 32], e) : 0u;
    }
    __syncthreads();
    ull lt = lane ? (~0ull >> (64u - lane)) : 0ull;
    ull* slab = lists + ((size_t)b * 4) * NPROP;
    if (cP) slab[0 * NPROP + sBase[0] + we[0][w] + (uint32_t)__popcll(mP & lt)] = entry;
    if (cH) slab[1 * NPROP + sBase[1] + we[1][w] + (uint32_t)__popcll(mH & lt)] = entry;
    if (cL) slab[2 * NPROP + sBase[2] + we[2][w] + (uint32_t)__popcll(mL & lt)] = entry;
    if (cI) slab[3 * NPROP + sBase[3] + we[3][w] + (uint32_t)__popcll(mI & lt)] = entry;
}

__global__ void __launch_bounds__(1024) k_select(
    const float* __restrict__ props, const float* __restrict__ gts,
    const ull* __restrict__ lists, const uint32_t* __restrict__ cnts,
    float* __restrict__ out)
{
#pragma clang fp contract(off)
    const int b = blockIdx.x;
    const int tid = threadIdx.x;
    __shared__ uint32_t hist[2048];      // 8 KB (radix fallback only)
    __shared__ ull      gat[GCAP];       // 4 KB
    __shared__ ull      selk[NSAMP];     // 2 KB
    __shared__ uint32_t sela[NSAMP];     // 1 KB
    __shared__ uint32_t sh_dig, sh_k, sh_cnt_in, gcnt, selc;
    __shared__ ull sh_thr;

    const ull* Ppos  = lists + ((size_t)b * 4 + 0) * NPROP;
    const ull* PnegH = lists + ((size_t)b * 4 + 1) * NPROP;
    const ull* PnegL = lists + ((size_t)b * 4 + 2) * NPROP;
    const ull* Pign  = lists + ((size_t)b * 4 + 3) * NPROP;
    const uint32_t npos = cnts[b * CSTR + 0];
    const uint32_t nH   = cnts[b * CSTR + 32];
    const uint32_t nL   = cnts[b * CSTR + 64];
    const uint32_t nig  = cnts[b * CSTR + 96];
    const uint32_t nneg = nH + nL;
    const uint32_t npn  = npos + nneg;
    if (tid == 0) selc = 0;
    __syncthreads();

    auto keyA_of = [](ull e) -> ull {    // raw (mant, invn): jnp stable argsort on r
        return (((e >> 21) & 0x7FFFFFull) << 14) | ((e >> 7) & 0x3FFFull);
    };

    auto locate = [&](uint32_t k) {      // boundary bin for k-th largest, wave 0
        if (tid < 64) {
            const uint32_t lane = (uint32_t)tid;
            uint32_t cs = 0;
            if (lane < 32) {
                const uint32_t base = lane * 64u;
                #pragma unroll 8
                for (uint32_t i = 0; i < 64; i++) cs += hist[base + i];
            }
            uint32_t s = cs;
            #pragma unroll
            for (int off = 1; off < 32; off <<= 1) {
                uint32_t t = __shfl_down(s, off);
                if (lane + off < 32) s += t;
            }
            uint32_t sExcl = s - cs;
            bool cond = (lane < 32) && (sExcl < k) && (k <= s);
            ull ball = __ballot(cond);
            uint32_t cstar = (uint32_t)(__ffsll((unsigned long long)ball) - 1);
            uint32_t kc = (uint32_t)__shfl((int)(k - sExcl), (int)cstar);
            uint32_t val = hist[cstar * 64u + lane];
            uint32_t fi = val;
            #pragma unroll
            for (int off = 1; off < 64; off <<= 1) {
                uint32_t t = __shfl_down(fi, off);
                if (lane + off < 64) fi += t;
            }
            uint32_t fExcl = fi - val;
            bool cond2 = (fExcl < kc) && (kc <= fi);
            ull ball2 = __ballot(cond2);
            uint32_t bstar = (uint32_t)(__ffsll((unsigned long long)ball2) - 1);
            if (lane == bstar) {
                sh_dig = cstar * 64u + lane;
                sh_k = kc - fExcl;
                sh_cnt_in = val;
            }
        }
    };

    // select k-th largest over m elements (key/elig via functor)
    auto radix = [&](auto&& kf, uint32_t m, uint32_t k, int shift) -> ull {
        if (m <= GCAP) {   // direct path: gather all eligible, rank-select
            if (tid == 0) gcnt = 0;
            __syncthreads();
            for (uint32_t j = tid; j < m; j += 1024) {
                bool e; ull key = kf(j, e);
                if (e) { uint32_t s = atomicAdd(&gcnt, 1u); gat[s] = key; }
            }
            __syncthreads();
            uint32_t gc = gcnt;
            if (tid < (int)gc) {
                ull x = gat[tid];
                uint32_t r = 0;
                for (uint32_t j = 0; j < gc; j++) r += (gat[j] > x);
                if (r == k - 1) sh_thr = x;
            }
            __syncthreads();
            return sh_thr;
        }
        ull prefix = 0, mask = 0;
        for (;;) {
            hist[tid] = 0; hist[tid + 1024] = 0;
            __syncthreads();
            for (uint32_t j = tid; j < m; j += 1024) {
                bool e; ull key = kf(j, e);
                if (e && ((key ^ prefix) & mask) == 0)
                    atomicAdd(&hist[(uint32_t)(key >> shift) & 2047u], 1u);
            }
            __syncthreads();
            locate(k);
            __syncthreads();
            uint32_t dig = sh_dig, kk = sh_k, cnt = sh_cnt_in;
            prefix |= ((ull)dig) << shift;
            mask   |= 2047ull << shift;
            if (cnt <= GCAP || shift == 0) {
                if (tid == 0) gcnt = 0;
                __syncthreads();
                for (uint32_t j = tid; j < m; j += 1024) {
                    bool e; ull key = kf(j, e);
                    if (e && ((key ^ prefix) & mask) == 0) {
                        uint32_t s = atomicAdd(&gcnt, 1u);
                        if (s < GCAP) gat[s] = key;
                    }
                }
                __syncthreads();
                uint32_t gc = (gcnt < GCAP) ? gcnt : GCAP;
                if (tid < (int)gc) {
                    ull x = gat[tid];
                    uint32_t r = 0;
                    for (uint32_t j = 0; j < gc; j++) r += (gat[j] > x);
                    if (r == kk - 1) sh_thr = x;
                }
                __syncthreads();
                return sh_thr;
            } else {
                k = kk;
                shift = (shift >= 11) ? shift - 11 : 0;
                __syncthreads();
            }
        }
    };

    // ---- phase 0: thrA = 64th-largest keyA among positives (only if npos > 64)
    ull thrA = 0;
    if (npos > NFG) {
        thrA = radix([&](uint32_t j, bool& e) -> ull {
            e = true; return keyA_of(Ppos[j]); }, npos, NFG, 26);
    }

    // exact jnp prio keys: f32 bits of (cls + r), rounding included
    auto keyB_pos = [&](ull ent) -> ull {
        uint32_t mant = (uint32_t)((ent >> 21) & 0x7FFFFFull);
        uint32_t invn = (uint32_t)((ent >> 7) & 0x3FFFull);
        float r = __uint_as_float(0x3F800000u | mant) - 1.0f;
        uint32_t cls = (keyA_of(ent) >= thrA) ? 3u : 1u;
        float prio = (float)cls + r;
        return (((ull)__float_as_uint(prio)) << 14) | (ull)invn;
    };
    auto keyB_neg = [](ull ent) -> ull {
        uint32_t mant = (uint32_t)((ent >> 21) & 0x7FFFFFull);
        uint32_t invn = (uint32_t)((ent >> 7) & 0x3FFFull);
        float r = __uint_as_float(0x3F800000u | mant) - 1.0f;
        float prio = 2.0f + r;
        return (((ull)__float_as_uint(prio)) << 14) | (ull)invn;
    };
    auto keyB_ign = [](ull ent) -> ull {
        uint32_t mant = (uint32_t)((ent >> 21) & 0x7FFFFFull);
        uint32_t invn = (uint32_t)((ent >> 7) & 0x3FFFull);
        float r = __uint_as_float(0x3F800000u | mant) - 1.0f;
        float prio = 0.0f + r;
        return (((ull)__float_as_uint(prio)) << 14) | (ull)invn;
    };

    // ---- phase 1: threshold for the 256-cut (boundary class analytic)
    const uint32_t c3 = (npos < NFG) ? npos : NFG;
    const uint32_t c2 = nneg;
    uint32_t clsStar = (npn >= NSAMP) ? ((NSAMP <= c3 + c2) ? 2u : 1u) : 0u;
    bool scanL = true;
    const bool scanI = (clsStar == 0u);
    ull thrB = 0;
    if (clsStar == 2u) {
        uint32_t k2 = NSAMP - c3;
        if (nH >= k2) {     // usual: top negatives are all in the high slab
            scanL = false;  // negL keys provably < any negH key (strict sep at NEGT)
            thrB = radix([&](uint32_t j, bool& e) -> ull {
                e = true; return keyB_neg(PnegH[j]); }, nH, k2, 25);
        } else {            // fallback: virtual concat of both neg slabs
            thrB = radix([&](uint32_t j, bool& e) -> ull {
                e = true; return keyB_neg(j < nH ? PnegH[j] : PnegL[j - nH]); },
                nneg, k2, 25);
        }
    } else if (clsStar == 1u) {
        uint32_t k1 = NSAMP - c3 - c2;
        thrB = radix([&](uint32_t j, bool& e) -> ull {
            ull kb = keyB_pos(Ppos[j]);
            e = ((kb >> 14) < 0x40000000ull);   // cls1 only (prio < 2.0)
            return kb; }, npos, k1, 26);
    } else {
        uint32_t k0 = NSAMP - npn;
        thrB = radix([&](uint32_t j, bool& e) -> ull {
            e = true; return keyB_ign(Pign[j]); }, nig, k0, 34);
    }
    __syncthreads();

    // ---- compact: exactly NSAMP keys (keys unique)
    auto push = [&](ull key, ull ent, uint32_t fg) {
        uint32_t s = atomicAdd(&selc, 1u);
        if (s < NSAMP) { selk[s] = key; sela[s] = (fg << 7) | (uint32_t)(ent & 0x7Full); }
    };
    for (uint32_t j = tid; j < npos; j += 1024) {
        ull ent = Ppos[j]; ull key = keyB_pos(ent);
        if (clsStar == 0u || key >= thrB) push(key, ent, 1u);
    }
    for (uint32_t j = tid; j < nH; j += 1024) {
        ull ent = PnegH[j]; ull key = keyB_neg(ent);
        if (clsStar == 0u || key >= thrB) push(key, ent, 0u);
    }
    if (scanL) {
        for (uint32_t j = tid; j < nL; j += 1024) {
            ull ent = PnegL[j]; ull key = keyB_neg(ent);
            if (clsStar == 0u || key >= thrB) push(key, ent, 0u);
        }
    }
    if (scanI) {
        for (uint32_t j = tid; j < nig; j += 1024) {
            ull ent = Pign[j]; ull key = keyB_ign(ent);
            if (key >= thrB) push(key, ent, 0u);
        }
    }
    __syncthreads();

    // ---- rank-scatter: output row = count of greater keys (desc sort position)
    if (tid < NSAMP) {
        ull x = selk[tid];
        uint32_t r = 0;
        for (int j = 0; j < NSAMP; j++) r += (selk[j] > x);
        uint32_t n = 16383u - (uint32_t)((x >> 0) & 0x3FFFull);
        uint32_t aux = sela[tid];
        uint32_t bg = aux & 0x7Fu;
        const int isfg = (int)((aux >> 7) & 1u);
        const float4 pb = ((const float4*)props)[(size_t)b * NPROP + n];
        const float4 gb = ((const float4*)gts)[(size_t)b * NGT + bg];
        const size_t O_ROI = 0;
        const size_t O_LBL = (size_t)BATCH * NSAMP * 4;
        const size_t O_TGT = O_LBL + (size_t)BATCH * NSAMP;
        const size_t O_INW = O_TGT + (size_t)BATCH * NSAMP * 4;
        const size_t O_OUW = O_INW + (size_t)BATCH * NSAMP * 4;
        const size_t row = (size_t)b * NSAMP + r;
        out[O_ROI + row * 4 + 0] = pb.x;
        out[O_ROI + row * 4 + 1] = pb.y;
        out[O_ROI + row * 4 + 2] = pb.z;
        out[O_ROI + row * 4 + 3] = pb.w;
        out[O_LBL + row] = isfg ? 1.0f : 0.0f;
        float rw  = pb.z - pb.x, rh = pb.w - pb.y;
        float gw  = gb.z - gb.x, gh = gb.w - gb.y;
        out[O_TGT + row * 4 + 0] = ((gb.x + gb.z) * 0.5f - (pb.x + pb.z) * 0.5f) / rw;
        out[O_TGT + row * 4 + 1] = ((gb.y + gb.w) * 0.5f - (pb.y + pb.w) * 0.5f) / rh;
        out[O_TGT + row * 4 + 2] = logf(gw / rw);
        out[O_TGT + row * 4 + 3] = logf(gh / rh);
        float wv = isfg ? 1.0f : 0.0f;
        for (int c = 0; c < 4; c++) {
            out[O_INW + row * 4 + c] = wv;
            out[O_OUW + row * 4 + c] = wv;
        }
    }
}

extern "C" void kernel_launch(void* const* d_in, const int* in_sizes, int n_in,
                              void* d_out, int out_size, void* d_ws, size_t ws_size,
                              hipStream_t stream) {
    (void)in_sizes; (void)n_in; (void)out_size; (void)ws_size;
    const float* props = (const float*)d_in[0];
    const float* gts   = (const float*)d_in[1];
    ull* lists = (ull*)d_ws;                                       // 16*4*16384*8 = 8 MB
    uint32_t* cnts = (uint32_t*)((char*)d_ws + (size_t)BATCH * 4 * NPROP * 8);
    float* out = (float*)d_out;

    k_zero<<<1, 1024, 0, stream>>>(cnts);
    dim3 gridA(NPROP / 128, BATCH);
    k_compute<<<gridA, 256, 0, stream>>>(props, gts, lists, cnts);
    k_select<<<BATCH, 1024, 0, stream>>>(props, gts, lists, cnts, out);
}